// Round 12
// baseline (312.485 us; speedup 1.0000x reference)
//
#include <hip/hip_runtime.h>
#include <cstdint>
#include <cstddef>

#define BB 2048
#define LL 96
#define PP 96
#define NN 64
#define HSTRIDE 68   // u32 row stride for packed LDS tiles (64 + 4 pad, 16B-aligned)

typedef __attribute__((ext_vector_type(8))) short short8;  // 8 bf16 (4 VGPRs)
typedef __attribute__((ext_vector_type(4))) float f32x4;

union U4S8 { uint4 u; short8 s; };

__device__ __forceinline__ float siluf(float x) {
  return x * __builtin_amdgcn_rcpf(1.0f + __expf(-x));
}
__device__ __forceinline__ float tanhf_fast(float x) {
  return 1.0f - 2.0f * __builtin_amdgcn_rcpf(1.0f + __expf(2.0f * x));
}
__device__ __forceinline__ float rlane(float x, int l) {
  return __int_as_float(__builtin_amdgcn_readlane(__float_as_int(x), l));
}

// ---- DPP cross-lane ops (VALU pipe); HW-verified R7/R8 ----
template <int CTRL>
__device__ __forceinline__ float dppadd(float x) {
  int y = __builtin_amdgcn_update_dpp(0, __float_as_int(x), CTRL, 0xF, 0xF, false);
  return x + __int_as_float(y);
}
template <int CTRL>
__device__ __forceinline__ float dppmov(float x) {
  int y = __builtin_amdgcn_update_dpp(0, __float_as_int(x), CTRL, 0xF, 0xF, false);
  return __int_as_float(y);
}
__device__ __forceinline__ float wave_sum(float x) {
  x = dppadd<0xB1>(x);
  x = dppadd<0x4E>(x);
  x = dppadd<0x141>(x);
  x = dppadd<0x128>(x);
  x += __shfl_xor(x, 16, 64);
  x += __shfl_xor(x, 32, 64);
  return x;
}

// split fp32 -> (bf16 hi | bf16 lo) packed in one u32 (hi in top 16).
__device__ __forceinline__ uint32_t packsplit(float f) {
  uint32_t b = __float_as_uint(f);
  uint32_t h = b & 0xFFFF0000u;
  float r = f - __uint_as_float(h);
  return h | (__float_as_uint(r) >> 16);
}
// reconstruct fp32 (exact hi+lo sum)
__device__ __forceinline__ float unpackf(uint32_t p) {
  return __uint_as_float(p & 0xFFFF0000u) + __uint_as_float(p << 16);
}
__device__ __forceinline__ void splitpack2(float f0, float f1, uint32_t& dhi, uint32_t& dlo) {
  uint32_t b0 = __float_as_uint(f0), b1 = __float_as_uint(f1);
  uint32_t h0 = b0 & 0xFFFF0000u, h1 = b1 & 0xFFFF0000u;
  float r0 = f0 - __uint_as_float(h0), r1 = f1 - __uint_as_float(h1);
  dhi = (h0 >> 16) | h1;
  dlo = (__float_as_uint(r0) >> 16) | (__float_as_uint(r1) & 0xFFFF0000u);
}
__device__ __forceinline__ void unpack2(uint32_t p0, uint32_t p1, uint32_t& dhi, uint32_t& dlo) {
  dhi = (p0 >> 16) | (p1 & 0xFFFF0000u);
  dlo = (p0 & 0xFFFFu) | (p1 << 16);
}
__device__ __forceinline__ void readfrag(const uint32_t* p, short8& hi, short8& lo) {
  uint4 pa = *(const uint4*)p;
  uint4 pb = *(const uint4*)(p + 4);
  U4S8 h, l;
  unpack2(pa.x, pa.y, h.u.x, l.u.x);
  unpack2(pa.z, pa.w, h.u.y, l.u.y);
  unpack2(pb.x, pb.y, h.u.z, l.u.z);
  unpack2(pb.z, pb.w, h.u.w, l.u.w);
  hi = h.s; lo = l.s;
}
// 3-term split-bf16 product over 2 k-steps: acc += A*B (~fp32 accuracy)
__device__ __forceinline__ f32x4 mm_split(f32x4 acc, const short8* Ah, const short8* Al,
                                          const short8* Bh, const short8* Bl) {
  acc = __builtin_amdgcn_mfma_f32_16x16x32_bf16(Ah[0], Bh[0], acc, 0, 0, 0);
  acc = __builtin_amdgcn_mfma_f32_16x16x32_bf16(Ah[1], Bh[1], acc, 0, 0, 0);
  acc = __builtin_amdgcn_mfma_f32_16x16x32_bf16(Al[0], Bh[0], acc, 0, 0, 0);
  acc = __builtin_amdgcn_mfma_f32_16x16x32_bf16(Al[1], Bh[1], acc, 0, 0, 0);
  acc = __builtin_amdgcn_mfma_f32_16x16x32_bf16(Ah[0], Bl[0], acc, 0, 0, 0);
  acc = __builtin_amdgcn_mfma_f32_16x16x32_bf16(Ah[1], Bl[1], acc, 0, 0, 0);
  return acc;
}

// ---- K1: fused x_proj + conv/compression/v/z0 (2 batches = 192 tok/block) --
// x_old never touches HBM: the 5-layer MLP leaves packed activations in hbuf;
// the k_hist tail (dilated conv + 8x6144 compression + v-MLP + z0) runs from
// LDS. Single wbuf (2 barriers/layer); LDS ~71 KB -> 2 blocks/CU.
__global__ __launch_bounds__(256, 2) void k_front(
    const float* __restrict__ x,
    const float* __restrict__ w0, const float* __restrict__ b0,
    const float* __restrict__ w1, const float* __restrict__ b1,
    const float* __restrict__ w2, const float* __restrict__ b2,
    const float* __restrict__ w3, const float* __restrict__ b3,
    const float* __restrict__ w4, const float* __restrict__ b4,
    const float* __restrict__ conv_w, const float* __restrict__ conv_b,
    const float* __restrict__ comp_w, const float* __restrict__ comp_b,
    const float* __restrict__ xw0, const float* __restrict__ xb0,
    const float* __restrict__ xw1, const float* __restrict__ xb1,
    float* __restrict__ a0_o, float* __restrict__ v_o, float* __restrict__ z0_o,
    float* __restrict__ out)
{
  __shared__ uint32_t hbuf[192 * HSTRIDE];  // 52224 B: activations then x_old
  __shared__ uint32_t wbuf[64 * HSTRIDE];   // 17408 B: current layer weights
  __shared__ float bs[320];
  __shared__ float red[32];
  __shared__ float z0s[64];
  __shared__ float hid[64];

  int tid = threadIdx.x;
  int wave = tid >> 6, lane = tid & 63;
  int quad = lane >> 4, m16 = lane & 15;
  size_t tokBase = (size_t)blockIdx.x * 192;

  // x_rec copy: 192 tok * 8 = 1536 floats = 384 float4 per block (guarded)
  #pragma unroll
  for (int i = 0; i < 2; ++i) {
    int t4 = i * 256 + tid;
    if (t4 < 384) {
      size_t e = tokBase * 8 + (size_t)t4 * 4;
      *(float4*)(out + e) = *(const float4*)(x + e);
    }
  }
  if (tid < 64) {
    bs[tid]       = b0[tid];
    bs[64 + tid]  = b1[tid];
    bs[128 + tid] = b2[tid];
    bs[192 + tid] = b3[tid];
    bs[256 + tid] = b4[tid];
  }
  __syncthreads();

  // ---- layer 0: [192x8] @ w0^T, K padded to 32; 3 M-tiles per wave ----
  short8 A0h[3], A0l[3];
  #pragma unroll
  for (int mt = 0; mt < 3; ++mt) {
    U4S8 h, l;
    h.u = make_uint4(0, 0, 0, 0); l.u = make_uint4(0, 0, 0, 0);
    if (quad == 0) {
      const float* xp = x + (tokBase + wave * 48 + mt * 16 + m16) * 8;
      float4 xa = *(const float4*)xp;
      float4 xb = *(const float4*)(xp + 4);
      splitpack2(xa.x, xa.y, h.u.x, l.u.x);
      splitpack2(xa.z, xa.w, h.u.y, l.u.y);
      splitpack2(xb.x, xb.y, h.u.z, l.u.z);
      splitpack2(xb.z, xb.w, h.u.w, l.u.w);
    }
    A0h[mt] = h.s; A0l[mt] = l.s;
  }
  {
    f32x4 acc[3][4];
    #pragma unroll
    for (int mt = 0; mt < 3; ++mt)
      #pragma unroll
      for (int nt = 0; nt < 4; ++nt) {
        float bv = bs[nt * 16 + m16];
        acc[mt][nt] = (f32x4){bv, bv, bv, bv};
      }
    #pragma unroll
    for (int nt = 0; nt < 4; ++nt) {
      U4S8 h, l;
      h.u = make_uint4(0, 0, 0, 0); l.u = make_uint4(0, 0, 0, 0);
      if (quad == 0) {
        const float* wp = w0 + (nt * 16 + m16) * 8;
        float4 wa = *(const float4*)wp;
        float4 wb = *(const float4*)(wp + 4);
        splitpack2(wa.x, wa.y, h.u.x, l.u.x);
        splitpack2(wa.z, wa.w, h.u.y, l.u.y);
        splitpack2(wb.x, wb.y, h.u.z, l.u.z);
        splitpack2(wb.z, wb.w, h.u.w, l.u.w);
      }
      #pragma unroll
      for (int mt = 0; mt < 3; ++mt) {
        acc[mt][nt] = __builtin_amdgcn_mfma_f32_16x16x32_bf16(A0h[mt], h.s, acc[mt][nt], 0, 0, 0);
        acc[mt][nt] = __builtin_amdgcn_mfma_f32_16x16x32_bf16(A0l[mt], h.s, acc[mt][nt], 0, 0, 0);
        acc[mt][nt] = __builtin_amdgcn_mfma_f32_16x16x32_bf16(A0h[mt], l.s, acc[mt][nt], 0, 0, 0);
      }
    }
    #pragma unroll
    for (int mt = 0; mt < 3; ++mt)
      #pragma unroll
      for (int nt = 0; nt < 4; ++nt)
        #pragma unroll
        for (int r = 0; r < 4; ++r) {
          float s = siluf(acc[mt][nt][r]);
          hbuf[(wave * 48 + mt * 16 + quad * 4 + r) * HSTRIDE + nt * 16 + m16] = packsplit(s);
        }
  }

  // ---- layers 1..4: single wbuf, 2 barriers/layer; hbuf rows wave-private --
  const float* Ws[4] = {w1, w2, w3, w4};
  #pragma unroll 1
  for (int lyr = 0; lyr < 4; ++lyr) {
    const float* w = Ws[lyr];
    #pragma unroll
    for (int i = 0; i < 4; ++i) {
      int e4 = i * 256 + tid;
      int o = e4 >> 4, k = (e4 & 15) << 2;
      float4 wv = ((const float4*)w)[e4];
      *(uint4*)(wbuf + o * HSTRIDE + k) =
          make_uint4(packsplit(wv.x), packsplit(wv.y), packsplit(wv.z), packsplit(wv.w));
    }
    __syncthreads();   // staging visible

    short8 Ah[6], Al[6];
    #pragma unroll
    for (int mt = 0; mt < 3; ++mt)
      #pragma unroll
      for (int ks = 0; ks < 2; ++ks)
        readfrag(hbuf + (wave * 48 + mt * 16 + m16) * HSTRIDE + ks * 32 + quad * 8,
                 Ah[mt * 2 + ks], Al[mt * 2 + ks]);

    f32x4 acc[3][4];
    #pragma unroll
    for (int mt = 0; mt < 3; ++mt)
      #pragma unroll
      for (int nt = 0; nt < 4; ++nt) {
        float bv = bs[(lyr + 1) * 64 + nt * 16 + m16];
        acc[mt][nt] = (f32x4){bv, bv, bv, bv};
      }
    #pragma unroll
    for (int nt = 0; nt < 4; ++nt) {
      short8 Bh[2], Bl[2];
      readfrag(wbuf + (nt * 16 + m16) * HSTRIDE + quad * 8,      Bh[0], Bl[0]);
      readfrag(wbuf + (nt * 16 + m16) * HSTRIDE + 32 + quad * 8, Bh[1], Bl[1]);
      #pragma unroll
      for (int mt = 0; mt < 3; ++mt)
        acc[mt][nt] = mm_split(acc[mt][nt], &Ah[mt * 2], &Al[mt * 2], Bh, Bl);
    }
    __syncthreads();   // wbuf reads done -> next staging safe

    if (lyr < 3) {
      #pragma unroll
      for (int mt = 0; mt < 3; ++mt)
        #pragma unroll
        for (int nt = 0; nt < 4; ++nt)
          #pragma unroll
          for (int r = 0; r < 4; ++r) {
            float s = siluf(acc[mt][nt][r]);
            hbuf[(wave * 48 + mt * 16 + quad * 4 + r) * HSTRIDE + nt * 16 + m16] = packsplit(s);
          }
    } else {
      // final linear layer -> packed x_old rows stay in hbuf
      #pragma unroll
      for (int mt = 0; mt < 3; ++mt)
        #pragma unroll
        for (int nt = 0; nt < 4; ++nt)
          #pragma unroll
          for (int r = 0; r < 4; ++r)
            hbuf[(wave * 48 + mt * 16 + quad * 4 + r) * HSTRIDE + nt * 16 + m16] =
                packsplit(acc[mt][nt][r]);
    }
  }
  __syncthreads();   // x_old rows visible across waves

  // ---- fused k_hist tail: conv + compression + v + z0, 2 batches ----
  int cch = tid & 63;
  float cvw0 = conv_w[cch * 3], cvw1 = conv_w[cch * 3 + 1], cvw2 = conv_w[cch * 3 + 2];
  float cvb = conv_b[cch];

  #pragma unroll 1
  for (int bb = 0; bb < 2; ++bb) {
    int base = bb * 96;
    int bglob = blockIdx.x * 2 + bb;
    float acc8[8];
    #pragma unroll
    for (int q = 0; q < 8; ++q) acc8[q] = 0.f;
    #pragma unroll 1
    for (int j = 0; j < 24; ++j) {
      int e = j * 256 + tid;
      int t = e >> 6;
      float s = unpackf(hbuf[(base + t) * HSTRIDE + cch]) * cvw0 + cvb;
      if (t + 2 < LL) s += unpackf(hbuf[(base + t + 2) * HSTRIDE + cch]) * cvw1;
      if (t + 4 < LL) s += unpackf(hbuf[(base + t + 4) * HSTRIDE + cch]) * cvw2;
      float hv = siluf(s);
      #pragma unroll
      for (int q = 0; q < 8; ++q) acc8[q] += hv * comp_w[q * 6144 + e];
    }
    #pragma unroll
    for (int q = 0; q < 8; ++q) acc8[q] = dppadd<0xB1>(acc8[q]);
    #pragma unroll
    for (int q = 0; q < 8; ++q) acc8[q] = dppadd<0x4E>(acc8[q]);
    #pragma unroll
    for (int q = 0; q < 8; ++q) acc8[q] = dppadd<0x141>(acc8[q]);
    #pragma unroll
    for (int q = 0; q < 8; ++q) acc8[q] = dppadd<0x128>(acc8[q]);
    #pragma unroll
    for (int q = 0; q < 8; ++q) acc8[q] += __shfl_xor(acc8[q], 16, 64);
    #pragma unroll
    for (int q = 0; q < 8; ++q) acc8[q] += __shfl_xor(acc8[q], 32, 64);
    if (lane < 8) {
      float sel = acc8[0];
      #pragma unroll
      for (int q = 1; q < 8; ++q) sel = (lane == q) ? acc8[q] : sel;
      red[wave * 8 + lane] = sel;
    }
    if (tid < 64) z0s[tid] = unpackf(hbuf[(base + 95) * HSTRIDE + tid]);
    __syncthreads();
    if (tid < 8)
      a0_o[bglob * 8 + tid] = red[tid] + red[8 + tid] + red[16 + tid] + red[24 + tid] + comp_b[tid];
    if (tid < 64) {
      float a2 = xb0[tid];
      #pragma unroll 8
      for (int k = 0; k < 64; ++k) a2 += xw0[tid * 64 + k] * z0s[k];
      hid[tid] = siluf(a2);
    }
    __syncthreads();
    float vr = 0.f;
    if (tid < 64) {
      vr = xb1[tid];
      #pragma unroll 8
      for (int k = 0; k < 64; ++k) vr += xw1[tid * 64 + k] * hid[k];
    }
    float s2 = wave_sum(vr * vr);
    if (tid < 64) {
      float nrm = sqrtf(s2) + 1e-8f;
      v_o[bglob * 64 + tid] = vr / nrm;
      z0_o[bglob * 64 + tid] = z0s[tid];
    }
    __syncthreads();   // red/z0s/hid reusable for bb=1
  }
}

// ------------- K3: 96-step ODE scan (R8/R10 version, 59 us) -----------------
__global__ __launch_bounds__(256) void k_scan(
    const float* __restrict__ a0_i, const float* __restrict__ v_i, const float* __restrict__ z0_i,
    const float* __restrict__ nw0, const float* __restrict__ nb0_p,
    const float* __restrict__ nw1, const float* __restrict__ nb1_p,
    const float* __restrict__ lw0, const float* __restrict__ lb0_p,
    const float* __restrict__ lw1, const float* __restrict__ lb1_p,
    const float* __restrict__ spanA, float* __restrict__ atraj, uint32_t* __restrict__ ztraj)
{
  __shared__ float hshm[4 * 72];
  int tid = threadIdx.x;
  int lane = tid & 63;
  int wv = tid >> 6;
  int b = blockIdx.x * 4 + wv;
  float dt = fminf(fmaxf(spanA[0], 1e-8f), 7.0f);
  int i8 = lane & 7;
  int oct = lane >> 3;
  float* hs = hshm + wv * 72;

  float w0r[8], w1L[8], g0r[8], d1r[8];
  #pragma unroll
  for (int i = 0; i < 8; ++i) w0r[i] = nw0[lane * 8 + i];
  #pragma unroll
  for (int j = 0; j < 8; ++j) w1L[j] = nw1[i8 * 64 + oct * 8 + j];
  #pragma unroll
  for (int i = 0; i < 8; ++i) g0r[i] = lw0[i8 * 8 + i];
  #pragma unroll
  for (int i = 0; i < 8; ++i) d1r[i] = lw1[lane * 8 + i];
  float nb0 = nb0_p[lane];
  float nb1o = nb1_p[i8];
  float lb0o = lb0_p[i8];
  float lb1 = lb1_p[lane];
  float v = v_i[b * 64 + lane];
  float z = z0_i[b * 64 + lane];
  float a_own = a0_i[b * 8 + i8];
  float t0 = wave_sum(v * z);
  float w = z - 2.0f * t0 * v;
  float a_s[8];
  #pragma unroll
  for (int i = 0; i < 8; ++i) a_s[i] = rlane(a_own, i);

  float* ab = atraj + (size_t)b * (PP * 8);
  uint32_t* zb = ztraj + (size_t)b * (PP * NN);
  #pragma unroll 1
  for (int p = 0; p < PP; ++p) {
    float h = nb0;
    #pragma unroll
    for (int i = 0; i < 8; ++i) h += w0r[i] * a_s[i];
    h = siluf(h);
    hs[lane] = h;
    float4 h0 = *(const float4*)(hs + oct * 8);
    float4 h1 = *(const float4*)(hs + oct * 8 + 4);
    float psum = w1L[0] * h0.x + w1L[1] * h0.y + w1L[2] * h0.z + w1L[3] * h0.w
               + w1L[4] * h1.x + w1L[5] * h1.y + w1L[6] * h1.z + w1L[7] * h1.w;
    psum += __shfl_xor(psum, 8, 64);
    psum += __shfl_xor(psum, 16, 64);
    psum += __shfl_xor(psum, 32, 64);
    float da_own = tanhf_fast(psum + nb1o);
    float ga = lb0o;
    #pragma unroll
    for (int i = 0; i < 8; ++i) ga += g0r[i] * a_s[i];
    float g_own = siluf(ga);
    float d = lb1;
    #pragma unroll
    for (int j = 0; j < 8; ++j) d += d1r[j] * rlane(g_own, j);
    a_own += dt * da_own;
    #pragma unroll
    for (int i = 0; i < 8; ++i) a_s[i] = rlane(a_own, i);
    w *= (1.0f + dt * d);
    float t1 = wave_sum(v * w);
    float zv = w - 2.0f * t1 * v;
    if (lane < 8) ab[p * 8 + lane] = a_own;
    zb[p * 64 + lane] = packsplit(zv);
  }
}

// --------- K4: post nets (R10 version: register M, ebuf aliases wbuf) -------
__global__ __launch_bounds__(256, 4) void k_post(
    const float* __restrict__ atraj, const uint32_t* __restrict__ ztraj,
    const float* __restrict__ cw0, const float* __restrict__ cb0,
    const float* __restrict__ cw1, const float* __restrict__ cb1,
    const float* __restrict__ zw0, const float* __restrict__ zb0,
    const float* __restrict__ zw1, const float* __restrict__ zb1,
    float* __restrict__ out)
{
  __shared__ uint32_t wbuf[144 * HSTRIDE];  // rows 0..63 reused as ebuf
  __shared__ float    cw0s[64];
  __shared__ float    cb0s[8];
  __shared__ float    zb0s[64];
  __shared__ float    zb1s[8];

  int tid = threadIdx.x;
  int wave = tid >> 6, lane = tid & 63;
  int quad = lane >> 4, m16 = lane & 15;
  size_t tokBase = (size_t)blockIdx.x * 64;

  #pragma unroll
  for (int i = 0; i < 36; ++i) {
    int e = i * 256 + tid;
    int o = e >> 6, k = e & 63;
    float wv;
    if (o < 64)       wv = cw1[(((o >> 3) * 64 + k) << 3) + (o & 7)];
    else if (o < 72)  wv = cb1[(o - 64) * 64 + k];
    else if (o < 136) wv = zw0[(o - 72) * 64 + k];
    else              wv = zw1[(o - 136) * 64 + k];
    wbuf[o * HSTRIDE + k] = packsplit(wv);
  }
  if (tid < 64) cw0s[tid] = cw0[tid];
  if (tid < 8)  cb0s[tid] = cb0[tid];
  if (tid < 64) zb0s[tid] = zb0[tid];
  if (tid < 8)  zb1s[tid] = zb1[tid];
  __syncthreads();

  const uint32_t* zp = ztraj + (tokBase + wave * 16 + m16) * 64;
  short8 Ah[2], Al[2];
  readfrag(zp + quad * 8,      Ah[0], Al[0]);
  readfrag(zp + 32 + quad * 8, Ah[1], Al[1]);

  f32x4 acc1[5];
  #pragma unroll
  for (int nt = 0; nt < 5; ++nt) {
    short8 Bh[2], Bl[2];
    readfrag(wbuf + (nt * 16 + m16) * HSTRIDE + quad * 8,      Bh[0], Bl[0]);
    readfrag(wbuf + (nt * 16 + m16) * HSTRIDE + 32 + quad * 8, Bh[1], Bl[1]);
    f32x4 acc = (f32x4){0.f, 0.f, 0.f, 0.f};
    acc1[nt] = mm_split(acc, Ah, Al, Bh, Bl);
  }
  __syncthreads();  // rows 0..63 now reusable as ebuf

  uint32_t* ebuf = wbuf;
  #pragma unroll
  for (int nt = 0; nt < 4; ++nt) {
    short8 Bh[2], Bl[2];
    readfrag(wbuf + (72 + nt * 16 + m16) * HSTRIDE + quad * 8,      Bh[0], Bl[0]);
    readfrag(wbuf + (72 + nt * 16 + m16) * HSTRIDE + 32 + quad * 8, Bh[1], Bl[1]);
    f32x4 acc = (f32x4){0.f, 0.f, 0.f, 0.f};
    acc = mm_split(acc, Ah, Al, Bh, Bl);
    int m = nt * 16 + m16;
    float zbv = zb0s[m];
    #pragma unroll
    for (int r = 0; r < 4; ++r) {
      float e = siluf(acc[r] + zbv);
      ebuf[(wave * 16 + quad * 4 + r) * HSTRIDE + m] = packsplit(e);
    }
  }

  f32x4 acc3;
  {
    short8 Eh[2], El[2];
    readfrag(ebuf + (wave * 16 + m16) * HSTRIDE + quad * 8,      Eh[0], El[0]);
    readfrag(ebuf + (wave * 16 + m16) * HSTRIDE + 32 + quad * 8, Eh[1], El[1]);
    short8 Bh[2], Bl[2];
    int brow = 136 + (m16 & 7);
    readfrag(wbuf + brow * HSTRIDE + quad * 8,      Bh[0], Bl[0]);
    readfrag(wbuf + brow * HSTRIDE + 32 + quad * 8, Bh[1], Bl[1]);
    f32x4 acc = (f32x4){0.f, 0.f, 0.f, 0.f};
    acc3 = mm_split(acc, Eh, El, Bh, Bl);
  }

  int j = m16 & 7;
  float cwj[8];
  #pragma unroll
  for (int i = 0; i < 8; ++i) cwj[i] = cw0s[j * 8 + i];
  float cbj = cb0s[j];
  #pragma unroll
  for (int r = 0; r < 4; ++r) {
    size_t idx = tokBase + wave * 16 + quad * 4 + r;
    const float* ap = atraj + idx * 8;
    float4 a0v = *(const float4*)ap;
    float4 a1v = *(const float4*)(ap + 4);
    float g2v = cbj
      + cwj[0] * a0v.x + cwj[1] * a0v.y + cwj[2] * a0v.z + cwj[3] * a0v.w
      + cwj[4] * a1v.x + cwj[5] * a1v.y + cwj[6] * a1v.z + cwj[7] * a1v.w;
    g2v = siluf(g2v);
    float yc[4], qo[4];
    #pragma unroll
    for (int nt = 0; nt < 4; ++nt) {
      float p = acc1[nt][r] * g2v;
      p = dppadd<0xB1>(p);
      p = dppadd<0x4E>(p);
      p = dppadd<0x141>(p);
      yc[nt] = p;
      qo[nt] = dppmov<0x128>(p);
    }
    if (m16 < 8) {
      int cc = m16;
      int nt = cc >> 1;
      float ye = (nt == 0) ? yc[0] : (nt == 1) ? yc[1] : (nt == 2) ? yc[2] : yc[3];
      float yo = (nt == 0) ? qo[0] : (nt == 1) ? qo[1] : (nt == 2) ? qo[2] : qo[3];
      float y = (cc & 1) ? yo : ye;
      y += acc1[4][r] + acc3[r] + zb1s[cc];
      out[(size_t)(BB * LL * 8) + idx * 8 + cc] = y;
    }
  }
}

extern "C" void kernel_launch(void* const* d_in, const int* in_sizes, int n_in,
                              void* d_out, int out_size, void* d_ws, size_t ws_size,
                              hipStream_t stream) {
  const float* x      = (const float*)d_in[0];
  const float* xp_w0  = (const float*)d_in[1];
  const float* xp_b0  = (const float*)d_in[2];
  const float* xp_w1  = (const float*)d_in[3];
  const float* xp_b1  = (const float*)d_in[4];
  const float* xp_w2  = (const float*)d_in[5];
  const float* xp_b2  = (const float*)d_in[6];
  const float* xp_w3  = (const float*)d_in[7];
  const float* xp_b3  = (const float*)d_in[8];
  const float* xp_w4  = (const float*)d_in[9];
  const float* xp_b4  = (const float*)d_in[10];
  const float* xpp_w0 = (const float*)d_in[11];
  const float* xpp_b0 = (const float*)d_in[12];
  const float* xpp_w1 = (const float*)d_in[13];
  const float* xpp_b1 = (const float*)d_in[14];
  const float* conv_w = (const float*)d_in[15];
  const float* conv_b = (const float*)d_in[16];
  const float* span_A = (const float*)d_in[17];
  const float* comp_w = (const float*)d_in[18];
  const float* comp_b = (const float*)d_in[19];
  const float* net_w0 = (const float*)d_in[20];
  const float* net_b0 = (const float*)d_in[21];
  const float* net_w1 = (const float*)d_in[22];
  const float* net_b1 = (const float*)d_in[23];
  const float* lo_w0  = (const float*)d_in[24];
  const float* lo_b0  = (const float*)d_in[25];
  const float* lo_w1  = (const float*)d_in[26];
  const float* lo_b1  = (const float*)d_in[27];
  const float* lc_w0  = (const float*)d_in[28];
  const float* lc_b0  = (const float*)d_in[29];
  const float* lc_w1  = (const float*)d_in[30];
  const float* lc_b1  = (const float*)d_in[31];
  const float* lz_w0  = (const float*)d_in[32];
  const float* lz_b0  = (const float*)d_in[33];
  const float* lz_w1  = (const float*)d_in[34];
  const float* lz_b1  = (const float*)d_in[35];

  float*    ws    = (float*)d_ws;
  uint32_t* ztraj = (uint32_t*)ws;         // (B,P,64) packed u32
  float*    atraj = ws + 12582912;         // (B,P,8)
  float*    a0    = ws + 14155776;         // (B,8)
  float*    vv    = a0 + 2048 * 8;         // (B,64)
  float*    z0    = vv + 2048 * 64;        // (B,64)
  float*    out   = (float*)d_out;

  hipLaunchKernelGGL(k_front, dim3(1024), dim3(256), 0, stream,
                     x, xp_w0, xp_b0, xp_w1, xp_b1, xp_w2, xp_b2, xp_w3, xp_b3,
                     xp_w4, xp_b4, conv_w, conv_b, comp_w, comp_b,
                     xpp_w0, xpp_b0, xpp_w1, xpp_b1, a0, vv, z0, out);
  hipLaunchKernelGGL(k_scan, dim3(512), dim3(256), 0, stream,
                     a0, vv, z0, net_w0, net_b0, net_w1, net_b1,
                     lo_w0, lo_b0, lo_w1, lo_b1, span_A, atraj, ztraj);
  hipLaunchKernelGGL(k_post, dim3(3072), dim3(256), 0, stream,
                     atraj, ztraj, lc_w0, lc_b0, lc_w1, lc_b1,
                     lz_w0, lz_b0, lz_w1, lz_b1, out);
}